// Round 8
// baseline (151.937 us; speedup 1.0000x reference)
//
#include <hip/hip_runtime.h>

typedef _Float16 h8v __attribute__((ext_vector_type(8)));
typedef float f4v __attribute__((ext_vector_type(4)));

#define RS 104   // halves per LDS row (208 B, 16B-aligned)
#define SD 52    // dwords per row
#define LDS_DW (96 * SD + 16)   // 96 rows + 64B tail pad (A-read overflow)

__device__ __forceinline__ unsigned pk2f(float a, float b) {
  unsigned short ha = __builtin_bit_cast(unsigned short, (_Float16)a);
  unsigned short hb = __builtin_bit_cast(unsigned short, (_Float16)b);
  return (unsigned)ha | ((unsigned)hb << 16);
}
__device__ __forceinline__ float2 upk(unsigned u) {
  _Float16 lo = __builtin_bit_cast(_Float16, (unsigned short)(u & 0xffffu));
  _Float16 hi = __builtin_bit_cast(_Float16, (unsigned short)(u >> 16));
  return make_float2((float)lo, (float)hi);
}

// prep: blocks [0,1563): 8 threads/word -> embh f16 rows, 64 dw = 256B
// (HBM-line-aligned for the random gather; dw 50..63 zero) + pw = exact f32
// lvl-0 projection. blocks [1563,1627): Wlf f16 [128][128]; block 1563 zeroes
// cnts (re-zeroed every graph replay -> re-poison safe).
__global__ void prep_kernel(const float* __restrict__ Wl, const float* __restrict__ emb,
                            const float* __restrict__ Wp, const float* __restrict__ bp,
                            unsigned short* __restrict__ Wlf, unsigned* __restrict__ embh,
                            float2* __restrict__ pw, unsigned* __restrict__ cnts) {
  const long t = (long)blockIdx.x * 256 + threadIdx.x;
  if (t < 400000L) {              // thread = (word w, slot q in 8-lane group)
    const int w = (int)(t >> 3), q = (int)(t & 7);
    const float4* row4 = (const float4*)(emb + (size_t)w * 100);
    uint2* ed = (uint2*)(embh + (size_t)w * 64);
    float q0 = 0.f, q1 = 0.f;
    #pragma unroll
    for (int m = 0; m < 4; ++m) {
      int j = q + 8 * m;          // group covers j = 8m..8m+7 -> 128B contiguous
      if (j < 25) {
        float4 v = row4[j];
        q0 = fmaf(v.x, Wp[4*j], fmaf(v.y, Wp[4*j+1],
             fmaf(v.z, Wp[4*j+2], fmaf(v.w, Wp[4*j+3], q0))));
        q1 = fmaf(v.x, Wp[100+4*j], fmaf(v.y, Wp[100+4*j+1],
             fmaf(v.z, Wp[100+4*j+2], fmaf(v.w, Wp[100+4*j+3], q1))));
        ed[j] = make_uint2(pk2f(v.x, v.y), pk2f(v.z, v.w));
      }
    }
    if (q < 7) ed[25 + q] = make_uint2(0u, 0u);   // pad dwords 50..63
    q0 += __shfl_xor(q0, 1, 64); q0 += __shfl_xor(q0, 2, 64); q0 += __shfl_xor(q0, 4, 64);
    q1 += __shfl_xor(q1, 1, 64); q1 += __shfl_xor(q1, 2, 64); q1 += __shfl_xor(q1, 4, 64);
    if (q == 0) pw[w] = make_float2(q0 + bp[0], q1 + bp[1]);
  } else {
    long j = t - 400128L;         // Wlf region: blocks 1563..1626
    if (j >= 0 && j < 128 * 128) {
      int o = (int)(j >> 7), k = (int)(j & 127);
      _Float16 v = (_Float16)0.f;
      if (o < 100 && k < 100) v = (_Float16)Wl[o * 100 + k];
      Wlf[j] = __builtin_bit_cast(unsigned short, v);
    }
    if (blockIdx.x == 1563 && threadIdx.x >= 192 && threadIdx.x < 240)
      cnts[threadIdx.x - 192] = 0u;   // 48 >= 33 counters
  }
}

// Vectorized B-fragment load from the f16 table: 8 x 16B per thread, L1-resident.
__device__ __forceinline__ void load_bfrags(
    const unsigned short* __restrict__ Wlf, const float* __restrict__ bl,
    h8v (&B0)[4], h8v (&B1)[4], float& bias0, float& bias1,
    int wave, int quad, int c16) {
  int col0 = wave * 32 + c16;
  int col1 = col0 + 16;
  bias0 = (col0 < 100) ? 2.0f * bl[col0] : 0.f;
  bias1 = (col1 < 100) ? 2.0f * bl[col1] : 0.f;
  const _Float16* w0 = (const _Float16*)Wlf + col0 * 128 + quad * 8;
  const _Float16* w1 = (const _Float16*)Wlf + col1 * 128 + quad * 8;
  B0[0] = *(const h8v*)(w0);      B0[1] = *(const h8v*)(w0 + 32);
  B0[2] = *(const h8v*)(w0 + 64); B0[3] = *(const h8v*)(w0 + 96);
  B1[0] = *(const h8v*)(w1);      B1[1] = *(const h8v*)(w1 + 32);
  B1[2] = *(const h8v*)(w1 + 64); B1[3] = *(const h8v*)(w1 + 96);
}

// One level: nOut rows. pairMode: A = srcE[r]+srcO[r]; else A = srcE[r].
// RS=104 < 128: k>=104 A-reads overflow into the next row; they multiply
// zero-padded Wlf weights -> exact zero iff the stale data is finite (LDS is
// zero-initialized at block start; all later values are finite f16).
// Stores guarded col<104 (cols 100..103 write zero, keeping pads zero).
__device__ __forceinline__ void mfma_level(
    const _Float16* srcE, const _Float16* srcO, bool pairMode,
    _Float16* dstE, _Float16* dstO, int nOut,
    const h8v (&B0)[4], const h8v (&B1)[4], float bias0, float bias1,
    int lane, int wave) {
  const int quad = lane >> 4, c16 = lane & 15;
  const int col0 = wave * 32 + c16, col1 = col0 + 16;
  const int tiles = (nOut + 15) >> 4;
  for (int rt = 0; rt < tiles; ++rt) {
    const int r = rt * 16 + c16;
    const h8v* pe = (const h8v*)(srcE + (size_t)r * RS + quad * 8);
    h8v A0, A1, A2, A3;
    if (pairMode) {
      const h8v* po = (const h8v*)(srcO + (size_t)r * RS + quad * 8);
      A0 = pe[0] + po[0];  A1 = pe[4] + po[4];
      A2 = pe[8] + po[8];  A3 = pe[12] + po[12];
    } else {
      A0 = pe[0]; A1 = pe[4]; A2 = pe[8]; A3 = pe[12];
    }
    f4v a0 = {bias0, bias0, bias0, bias0};
    f4v a1 = {bias1, bias1, bias1, bias1};
    a0 = __builtin_amdgcn_mfma_f32_16x16x32_f16(A0, B0[0], a0, 0, 0, 0);
    a0 = __builtin_amdgcn_mfma_f32_16x16x32_f16(A1, B0[1], a0, 0, 0, 0);
    a0 = __builtin_amdgcn_mfma_f32_16x16x32_f16(A2, B0[2], a0, 0, 0, 0);
    a0 = __builtin_amdgcn_mfma_f32_16x16x32_f16(A3, B0[3], a0, 0, 0, 0);
    a1 = __builtin_amdgcn_mfma_f32_16x16x32_f16(A0, B1[0], a1, 0, 0, 0);
    a1 = __builtin_amdgcn_mfma_f32_16x16x32_f16(A1, B1[1], a1, 0, 0, 0);
    a1 = __builtin_amdgcn_mfma_f32_16x16x32_f16(A2, B1[2], a1, 0, 0, 0);
    a1 = __builtin_amdgcn_mfma_f32_16x16x32_f16(A3, B1[3], a1, 0, 0, 0);
    #pragma unroll
    for (int rg = 0; rg < 4; ++rg) {
      int row = rt * 16 + quad * 4 + rg;
      _Float16* dr = ((row & 1) ? dstO : dstE) + (size_t)(row >> 1) * RS;
      if (col0 < 104) dr[col0] = (_Float16)fmaxf(a0[rg], 0.f);
      if (col1 < 104) dr[col1] = (_Float16)fmaxf(a1[rg], 0.f);
    }
  }
}

// Projection of nRows h-rows (E/O split) at level lvl, nodes gbase+tid.
// Wp read from global: indices compile-time -> wave-uniform s_loads, K$-resident.
__device__ __forceinline__ void proj_rows(
    const _Float16* E, const _Float16* O, int nRows, const float* __restrict__ Wp,
    float bp0, float bp1, int lvl, long gbase, float* __restrict__ out, int tid) {
  if (tid >= nRows) return;
  const unsigned* row = (const unsigned*)((tid & 1) ? O : E) + (size_t)(tid >> 1) * SD;
  float q0 = bp0, q1 = bp1;
  #pragma unroll
  for (int p = 0; p < 25; ++p) {
    uint2 u = ((const uint2*)row)[p];
    float2 a = upk(u.x), b = upk(u.y);
    q0 = fmaf(a.x, Wp[4*p], fmaf(a.y, Wp[4*p+1],
         fmaf(b.x, Wp[4*p+2], fmaf(b.y, Wp[4*p+3], q0))));
    q1 = fmaf(a.x, Wp[100+4*p], fmaf(a.y, Wp[100+4*p+1],
         fmaf(b.x, Wp[100+4*p+2], fmaf(b.y, Wp[100+4*p+3], q1))));
  }
  long g = gbase + tid;
  long pos = ((g + 1) << (lvl + 1)) - 2 - __popc((unsigned)g);
  out[2 * pos] = q0; out[2 * pos + 1] = q1;
}

// Stage nIn rows (agent-scope) into TE/TO, zero dest regions, run nLvl levels,
// proj levels firstLvl-1..firstLvl+nLvl-2, optional final proj + h-writeback.
__device__ void tree_phase(
    const unsigned* __restrict__ src, unsigned* __restrict__ hdst,
    _Float16* TE, _Float16* TO, _Float16* Eb, _Float16* Ob,
    const float* __restrict__ Wp, float bp0, float bp1,
    const h8v (&B0)[4], const h8v (&B1)[4], float bias0, float bias1,
    float* __restrict__ out, int firstLvl, int nLvl, int nIn, int finalProj,
    long blkg, int tid, int lane, int wave) {
  {   // stage 64 virtual rows (r<nIn real, rest zero) + zero dest regions
    unsigned* Ed = (unsigned*)TE; unsigned* Od = (unsigned*)TO;
    const int d = tid & 63;
    if (d < SD) {
      for (int r = tid >> 6; r < 64; r += 4) {
        unsigned val = 0u;
        if (r < nIn && d < 50)
          val = __hip_atomic_load(&src[(size_t)r * 50 + d], __ATOMIC_RELAXED,
                                  __HIP_MEMORY_SCOPE_AGENT);
        ((r & 1) ? Od : Ed)[(r >> 1) * SD + d] = val;
      }
      unsigned* Ed2 = (unsigned*)Eb; unsigned* Od2 = (unsigned*)Ob;
      for (int r = tid >> 6; r < 32; r += 4)
        ((r & 1) ? Od2 : Ed2)[(r >> 1) * SD + d] = 0u;
    }
  }
  __syncthreads();
  _Float16 *sE = TE, *sO = TO, *dE = Eb, *dO = Ob;
  int n = nIn >> 1;
  for (int p = 0; p < nLvl; ++p) {
    mfma_level(sE, sO, true, dE, dO, n, B0, B1, bias0, bias1, lane, wave);
    proj_rows(sE, sO, n * 2, Wp, bp0, bp1, firstLvl + p - 1,
              blkg * (n * 2), out, tid);
    __syncthreads();
    _Float16* t;
    t = sE; sE = dE; dE = t;
    t = sO; sO = dO; dO = t;
    n >>= 1;
  }
  int R = nIn >> nLvl;
  if (finalProj)
    proj_rows(sE, sO, R, Wp, bp0, bp1, firstLvl + nLvl - 1, blkg * R, out, tid);
  if (hdst) {
    for (int i = tid; i < R * 50; i += 256) {
      int r = i / 50, d2 = i % 50;
      unsigned val = ((const unsigned*)((r & 1) ? sO : sE))[(r >> 1) * SD + d2];
      __hip_atomic_store(&hdst[(size_t)blkg * R * 50 + i], val,
                         __ATOMIC_RELAXED, __HIP_MEMORY_SCOPE_AGENT);
    }
  }
  __syncthreads();  // drains hdst stores + LDS reusable
}

// Fused kernel: 64 leaves/block x 2048 blocks. LDS 20.4KB -> 8 blocks/CU
// capacity; launch_bounds(256,4) leaves VGPR cap at 128 so the allocator
// uses its natural ~64-88 regs (r6's forced cap of 64 caused the spill storm).
// Runtime occupancy = min(8 LDS, 512/VGPR) blocks/CU = 5-8.
__global__ __launch_bounds__(256, 4) void mega_kernel(
    const int* __restrict__ word_ids, const unsigned* __restrict__ embh,
    const float2* __restrict__ pw,
    const unsigned short* __restrict__ Wlf, const float* __restrict__ bl,
    const float* __restrict__ Wp, const float* __restrict__ bp,
    unsigned* __restrict__ h6g, unsigned* __restrict__ h12g,
    unsigned* __restrict__ cnts, float* __restrict__ out) {
  __shared__ _Float16 LB[2 * LDS_DW];   // 96 rows x 104 halves + tail pad
  __shared__ int claimS;
  _Float16* const S1 = LB;              // rows  0..31 (leaf S1 / tree TE)
  _Float16* const Ea = LB + 32 * RS;    // rows 32..47 (tree TO spans 32..63)
  _Float16* const Oa = LB + 48 * RS;    // rows 48..63
  _Float16* const Eb = LB + 64 * RS;    // rows 64..79
  _Float16* const Ob = LB + 80 * RS;    // rows 80..95

  const int tid = threadIdx.x, lane = tid & 63;
  const int wave = __builtin_amdgcn_readfirstlane(tid >> 6);
  const int quad = lane >> 4, c16 = lane & 15;
  const int blk = blockIdx.x;

  // ---- issue gather first (loads in flight during LDS zeroing) ----
  const int l4 = tid >> 2, q = tid & 3;       // leaf-in-block, quarter
  const int wid = word_ids[(size_t)blk * 64 + l4];
  const uint4* erow = (const uint4*)(embh + (size_t)wid * 64);  // 256B-aligned row
  uint4 w4[4];
  #pragma unroll
  for (int k = 0; k < 4; ++k) {
    int c = q + 4 * k;
    if (c < 13) w4[k] = erow[c];              // dw 0..51 only
  }
  float2 p0 = make_float2(0.f, 0.f);
  if (tid < 64) p0 = pw[word_ids[(size_t)blk * 64 + tid]];
  const float bp0 = bp[0], bp1 = bp[1];

  // ---- zero ALL of LDS once: every later stale read is finite f16
  //      (NaN-safety for the RS=104 A-read overflow; see mfma_level) ----
  {
    unsigned* lb = (unsigned*)LB;
    for (int i = tid; i < LDS_DW; i += 256) lb[i] = 0u;
  }
  __syncthreads();

  {   // pair-sum with sibling leaf (thread xor 4) via packed f16 adds -> S1
    unsigned* S1d = (unsigned*)S1;
    const int m = tid >> 3;                   // level-1 node 0..31
    #pragma unroll
    for (int k = 0; k < 4; ++k) {
      int c = q + 4 * k;
      if (c < 13) {
        uint4 u = w4[k], s;
        s.x = __shfl_xor(u.x, 4, 64); s.y = __shfl_xor(u.y, 4, 64);
        s.z = __shfl_xor(u.z, 4, 64); s.w = __shfl_xor(u.w, 4, 64);
        h8v hm = __builtin_bit_cast(h8v, u);
        h8v hs = __builtin_bit_cast(h8v, s);
        h8v sum = hm + hs;                    // v_pk_add_f16: correctly-rounded
        if ((tid & 4) == 0)
          *(uint4*)(S1d + (size_t)m * SD + c * 4) = __builtin_bit_cast(uint4, sum);
      }
    }
  }
  h8v B0[4], B1[4]; float bias0, bias1;
  load_bfrags(Wlf, bl, B0, B1, bias0, bias1, wave, quad, c16);

  // lvl-0 projection: precomputed exact f32 per-word values
  if (tid < 64) {
    long gL = (long)blk * 64 + tid;
    long pos = ((gL + 1) << 1) - 2 - __popc((unsigned)gL);
    out[2 * pos] = p0.x; out[2 * pos + 1] = p0.y;
  }
  __syncthreads();   // S1 ready

  // L1 (32 out): S1 pre-summed -> Ea/Oa
  mfma_level(S1, nullptr, false, Ea, Oa, 32, B0, B1, bias0, bias1, lane, wave);
  __syncthreads();
  // L2 (16) + proj l1
  mfma_level(Ea, Oa, true, Eb, Ob, 16, B0, B1, bias0, bias1, lane, wave);
  proj_rows(Ea, Oa, 32, Wp, bp0, bp1, 1, (long)blk * 32, out, tid);
  __syncthreads();
  // L3 (8) + proj l2
  mfma_level(Eb, Ob, true, Ea, Oa, 8, B0, B1, bias0, bias1, lane, wave);
  proj_rows(Eb, Ob, 16, Wp, bp0, bp1, 2, (long)blk * 16, out, tid);
  __syncthreads();
  // L4 (4) + proj l3
  mfma_level(Ea, Oa, true, Eb, Ob, 4, B0, B1, bias0, bias1, lane, wave);
  proj_rows(Ea, Oa, 8, Wp, bp0, bp1, 3, (long)blk * 8, out, tid);
  __syncthreads();
  // L5 (2) + proj l4
  mfma_level(Eb, Ob, true, Ea, Oa, 2, B0, B1, bias0, bias1, lane, wave);
  proj_rows(Eb, Ob, 4, Wp, bp0, bp1, 4, (long)blk * 4, out, tid);
  __syncthreads();
  // L6 (1) + proj l5
  mfma_level(Ea, Oa, true, Eb, Ob, 1, B0, B1, bias0, bias1, lane, wave);
  proj_rows(Ea, Oa, 2, Wp, bp0, bp1, 5, (long)blk * 2, out, tid);
  __syncthreads();
  // publish h6 row (node 0 -> Eb row 0); level-6 proj happens in tree phase
  if (tid < 50)
    __hip_atomic_store(&h6g[(size_t)blk * 50 + tid], ((unsigned*)Eb)[tid],
                       __ATOMIC_RELAXED, __HIP_MEMORY_SCOPE_AGENT);
  __syncthreads();   // drains h6g stores block-wide

  const int g = blk >> 6;
  if (tid == 0) {
    unsigned old = __hip_atomic_fetch_add(&cnts[g], 1u, __ATOMIC_RELAXED,
                                          __HIP_MEMORY_SCOPE_AGENT);
    claimS = (old == 63u);
  }
  __syncthreads();
  if (!claimS) return;

  // ---- group claimer (32 parallel): levels 7..12 (+ proj 6..11) -> h12 row g
  tree_phase(h6g + (size_t)g * 64 * 50, h12g, S1, Ea, Eb, Ob, Wp, bp0, bp1,
             B0, B1, bias0, bias1, out, 7, 6, 64, 0, (long)g, tid, lane, wave);

  if (tid == 0) {
    unsigned old = __hip_atomic_fetch_add(&cnts[32], 1u, __ATOMIC_RELAXED,
                                          __HIP_MEMORY_SCOPE_AGENT);
    claimS = (old == 31u);
  }
  __syncthreads();
  if (!claimS) return;

  // ---- final claimer: levels 13..17 (+ proj 12..16 + final proj 17) ----
  tree_phase(h12g, nullptr, S1, Ea, Eb, Ob, Wp, bp0, bp1,
             B0, B1, bias0, bias1, out, 13, 5, 32, 1, 0L, tid, lane, wave);
}

extern "C" void kernel_launch(void* const* d_in, const int* in_sizes, int n_in,
                              void* d_out, int out_size, void* d_ws, size_t ws_size,
                              hipStream_t stream) {
  const int*   word_ids = (const int*)  d_in[0];
  const float* emb      = (const float*)d_in[1];
  const float* Wl       = (const float*)d_in[2];
  const float* bl       = (const float*)d_in[3];
  const float* Wp       = (const float*)d_in[4];
  const float* bp       = (const float*)d_in[5];
  float* out = (float*)d_out;

  // workspace layout (~13.65 MB)
  unsigned*       embh = (unsigned*)d_ws;                            // 12,800,000 B
  float2*         pw   = (float2*)((char*)d_ws + 12800000);          //    400,000 B
  unsigned short* Wlf  = (unsigned short*)((char*)d_ws + 13200000);  //     32,768 B
  unsigned*       h6g  = (unsigned*)((char*)d_ws + 13232768);        //    409,600 B
  unsigned*       h12g = (unsigned*)((char*)d_ws + 13642368);        //      6,400 B
  unsigned*       cnts = (unsigned*)((char*)d_ws + 13648768);        //        256 B

  prep_kernel<<<1627, 256, 0, stream>>>(Wl, emb, Wp, bp, Wlf, embh, pw, cnts);
  mega_kernel<<<2048, 256, 0, stream>>>(word_ids, embh, pw, Wlf, bl, Wp, bp,
                                        h6g, h12g, cnts, out);
}

// Round 9
// 136.295 us; speedup vs baseline: 1.1148x; 1.1148x over previous
//
#include <hip/hip_runtime.h>

typedef _Float16 h8v __attribute__((ext_vector_type(8)));
typedef float f4v __attribute__((ext_vector_type(4)));

#define RS 136   // halves per LDS row (272 B, 16B-aligned, stride%32dw==4 -> 2-way max)
#define SD 68    // dwords per row

__device__ __forceinline__ unsigned pk2f(float a, float b) {
  unsigned short ha = __builtin_bit_cast(unsigned short, (_Float16)a);
  unsigned short hb = __builtin_bit_cast(unsigned short, (_Float16)b);
  return (unsigned)ha | ((unsigned)hb << 16);
}
__device__ __forceinline__ float2 upk(unsigned u) {
  _Float16 lo = __builtin_bit_cast(_Float16, (unsigned short)(u & 0xffffu));
  _Float16 hi = __builtin_bit_cast(_Float16, (unsigned short)(u >> 16));
  return make_float2((float)lo, (float)hi);
}

// prep v2 (BW-oriented): blocks [0,1563): 8 threads/word, coalesced 128B group
// loads / 64B group stores -> embh f16 rows (64 dw = 256B, dw 50..63 zero) +
// pw = exact f32 lvl-0 projection (3-step shfl_xor group reduce).
// blocks [1563,1627): Wlf f16 [128][128]; block 1563 zeroes cnts
// (re-zeroed every graph replay -> re-poison safe).
__global__ void prep_kernel(const float* __restrict__ Wl, const float* __restrict__ emb,
                            const float* __restrict__ Wp, const float* __restrict__ bp,
                            unsigned short* __restrict__ Wlf, unsigned* __restrict__ embh,
                            float2* __restrict__ pw, unsigned* __restrict__ cnts) {
  const long t = (long)blockIdx.x * 256 + threadIdx.x;
  if (t < 400000L) {              // thread = (word w, slot q in 8-lane group)
    const int w = (int)(t >> 3), q = (int)(t & 7);
    const float4* row4 = (const float4*)(emb + (size_t)w * 100);
    uint2* ed = (uint2*)(embh + (size_t)w * 64);
    float q0 = 0.f, q1 = 0.f;
    #pragma unroll
    for (int m = 0; m < 4; ++m) {
      int j = q + 8 * m;          // group covers j = 8m..8m+7 -> 128B contiguous
      if (j < 25) {
        float4 v = row4[j];
        q0 = fmaf(v.x, Wp[4*j], fmaf(v.y, Wp[4*j+1],
             fmaf(v.z, Wp[4*j+2], fmaf(v.w, Wp[4*j+3], q0))));
        q1 = fmaf(v.x, Wp[100+4*j], fmaf(v.y, Wp[100+4*j+1],
             fmaf(v.z, Wp[100+4*j+2], fmaf(v.w, Wp[100+4*j+3], q1))));
        ed[j] = make_uint2(pk2f(v.x, v.y), pk2f(v.z, v.w));
      }
    }
    if (q < 7) ed[25 + q] = make_uint2(0u, 0u);   // pad dwords 50..63
    q0 += __shfl_xor(q0, 1, 64); q0 += __shfl_xor(q0, 2, 64); q0 += __shfl_xor(q0, 4, 64);
    q1 += __shfl_xor(q1, 1, 64); q1 += __shfl_xor(q1, 2, 64); q1 += __shfl_xor(q1, 4, 64);
    if (q == 0) pw[w] = make_float2(q0 + bp[0], q1 + bp[1]);
  } else {
    long j = t - 400128L;         // Wlf region: blocks 1563..1626
    if (j >= 0 && j < 128 * 128) {
      int o = (int)(j >> 7), k = (int)(j & 127);
      _Float16 v = (_Float16)0.f;
      if (o < 100 && k < 100) v = (_Float16)Wl[o * 100 + k];
      Wlf[j] = __builtin_bit_cast(unsigned short, v);
    }
    if (blockIdx.x == 1563 && threadIdx.x >= 192 && threadIdx.x < 240)
      cnts[threadIdx.x - 192] = 0u;
  }
}

// Vectorized B-fragment load from the f16 table: 8 x 16B per thread, L1-resident.
__device__ __forceinline__ void load_bfrags(
    const unsigned short* __restrict__ Wlf, const float* __restrict__ bl,
    h8v (&B0)[4], h8v (&B1)[4], float& bias0, float& bias1,
    int wave, int quad, int c16) {
  int col0 = wave * 32 + c16;
  int col1 = col0 + 16;
  bias0 = (col0 < 100) ? 2.0f * bl[col0] : 0.f;
  bias1 = (col1 < 100) ? 2.0f * bl[col1] : 0.f;
  const _Float16* w0 = (const _Float16*)Wlf + col0 * 128 + quad * 8;
  const _Float16* w1 = (const _Float16*)Wlf + col1 * 128 + quad * 8;
  B0[0] = *(const h8v*)(w0);      B0[1] = *(const h8v*)(w0 + 32);
  B0[2] = *(const h8v*)(w0 + 64); B0[3] = *(const h8v*)(w0 + 96);
  B1[0] = *(const h8v*)(w1);      B1[1] = *(const h8v*)(w1 + 32);
  B1[2] = *(const h8v*)(w1 + 64); B1[3] = *(const h8v*)(w1 + 96);
}

// One level: nOut rows. pairMode: A = srcE[r] + srcO[r] (children 2r,2r+1);
// else A = srcE[r] (pre-summed). Output row -> (row&1 ? dstO : dstE)[row>>1].
__device__ __forceinline__ void mfma_level(
    const _Float16* srcE, const _Float16* srcO, bool pairMode,
    _Float16* dstE, _Float16* dstO, int nOut,
    const h8v (&B0)[4], const h8v (&B1)[4], float bias0, float bias1,
    int lane, int wave) {
  const int quad = lane >> 4, c16 = lane & 15;
  const int col0 = wave * 32 + c16, col1 = col0 + 16;
  const int tiles = (nOut + 15) >> 4;
  for (int rt = 0; rt < tiles; ++rt) {
    const int r = rt * 16 + c16;
    const h8v* pe = (const h8v*)(srcE + (size_t)r * RS + quad * 8);
    h8v A0, A1, A2, A3;
    if (pairMode) {
      const h8v* po = (const h8v*)(srcO + (size_t)r * RS + quad * 8);
      A0 = pe[0] + po[0];  A1 = pe[4] + po[4];
      A2 = pe[8] + po[8];  A3 = pe[12] + po[12];
    } else {
      A0 = pe[0]; A1 = pe[4]; A2 = pe[8]; A3 = pe[12];
    }
    f4v a0 = {bias0, bias0, bias0, bias0};
    f4v a1 = {bias1, bias1, bias1, bias1};
    a0 = __builtin_amdgcn_mfma_f32_16x16x32_f16(A0, B0[0], a0, 0, 0, 0);
    a0 = __builtin_amdgcn_mfma_f32_16x16x32_f16(A1, B0[1], a0, 0, 0, 0);
    a0 = __builtin_amdgcn_mfma_f32_16x16x32_f16(A2, B0[2], a0, 0, 0, 0);
    a0 = __builtin_amdgcn_mfma_f32_16x16x32_f16(A3, B0[3], a0, 0, 0, 0);
    a1 = __builtin_amdgcn_mfma_f32_16x16x32_f16(A0, B1[0], a1, 0, 0, 0);
    a1 = __builtin_amdgcn_mfma_f32_16x16x32_f16(A1, B1[1], a1, 0, 0, 0);
    a1 = __builtin_amdgcn_mfma_f32_16x16x32_f16(A2, B1[2], a1, 0, 0, 0);
    a1 = __builtin_amdgcn_mfma_f32_16x16x32_f16(A3, B1[3], a1, 0, 0, 0);
    #pragma unroll
    for (int rg = 0; rg < 4; ++rg) {
      int row = rt * 16 + quad * 4 + rg;
      _Float16* dr = ((row & 1) ? dstO : dstE) + (size_t)(row >> 1) * RS;
      dr[col0] = (_Float16)fmaxf(a0[rg], 0.f);
      dr[col1] = (_Float16)fmaxf(a1[rg], 0.f);
    }
  }
}

// Projection of nRows h-rows (E/O split) at level lvl, nodes gbase+tid.
// Wp read from global: indices compile-time -> wave-uniform s_loads, L1/K$-hot
// (validated bit-identical in r7).
__device__ __forceinline__ void proj_rows(
    const _Float16* E, const _Float16* O, int nRows, const float* __restrict__ Wp,
    float bp0, float bp1, int lvl, long gbase, float* __restrict__ out, int tid) {
  if (tid >= nRows) return;
  const unsigned* row = (const unsigned*)((tid & 1) ? O : E) + (size_t)(tid >> 1) * SD;
  float q0 = bp0, q1 = bp1;
  #pragma unroll
  for (int p = 0; p < 25; ++p) {
    uint2 u = ((const uint2*)row)[p];
    float2 a = upk(u.x), b = upk(u.y);
    q0 = fmaf(a.x, Wp[4*p], fmaf(a.y, Wp[4*p+1],
         fmaf(b.x, Wp[4*p+2], fmaf(b.y, Wp[4*p+3], q0))));
    q1 = fmaf(a.x, Wp[100+4*p], fmaf(a.y, Wp[100+4*p+1],
         fmaf(b.x, Wp[100+4*p+2], fmaf(b.y, Wp[100+4*p+3], q1))));
  }
  long g = gbase + tid;
  long pos = ((g + 1) << (lvl + 1)) - 2 - __popc((unsigned)g);
  out[2 * pos] = q0; out[2 * pos + 1] = q1;
}

// Stage nIn rows (agent-scope loads), run nLvl levels, proj levels, optional
// final proj, optional agent-scope h-row writeback. (r5 structure verbatim.)
__device__ void tree_phase(
    const unsigned* __restrict__ src, unsigned* __restrict__ hdst,
    _Float16* Ea, _Float16* Oa, _Float16* Eb, _Float16* Ob,
    const float* __restrict__ Wp, float bp0, float bp1,
    const h8v (&B0)[4], const h8v (&B1)[4], float bias0, float bias1,
    float* __restrict__ out, int firstLvl, int nLvl, int nIn, int finalProj,
    long blk, int tid, int lane, int wave) {
  {   // stage nIn rows + zero the rest of Ea/Oa (64 virtual rows x 64 dw)
    unsigned* Ed = (unsigned*)Ea; unsigned* Od = (unsigned*)Oa;
    for (int i = tid; i < 64 * 64; i += 256) {
      int r = i >> 6, d = i & 63;
      unsigned val = (r < nIn && d < 50)
          ? __hip_atomic_load(&src[(size_t)r * 50 + d], __ATOMIC_RELAXED,
                              __HIP_MEMORY_SCOPE_AGENT)
          : 0u;
      ((r & 1) ? Od : Ed)[(r >> 1) * SD + d] = val;
    }
    unsigned* Ed2 = (unsigned*)Eb; unsigned* Od2 = (unsigned*)Ob;
    for (int i = tid; i < 32 * 64; i += 256) {
      int r = i >> 6, d = i & 63;
      ((r & 1) ? Od2 : Ed2)[(r >> 1) * SD + d] = 0u;
    }
  }
  __syncthreads();
  _Float16 *sE = Ea, *sO = Oa, *dE = Eb, *dO = Ob;
  int n = nIn >> 1;
  for (int p = 0; p < nLvl; ++p) {
    mfma_level(sE, sO, true, dE, dO, n, B0, B1, bias0, bias1, lane, wave);
    proj_rows(sE, sO, n * 2, Wp, bp0, bp1, firstLvl + p - 1,
              blk * (n * 2), out, tid);
    __syncthreads();
    _Float16* t;
    t = sE; sE = dE; dE = t;
    t = sO; sO = dO; dO = t;
    n >>= 1;
  }
  int R = nIn >> nLvl;
  if (finalProj)
    proj_rows(sE, sO, R, Wp, bp0, bp1, firstLvl + nLvl - 1, blk * R, out, tid);
  if (hdst) {
    for (int i = tid; i < R * 50; i += 256) {
      int r = i / 50, d = i % 50;
      unsigned val = ((const unsigned*)((r & 1) ? sO : sE))[(r >> 1) * SD + d];
      __hip_atomic_store(&hdst[(size_t)blk * R * 50 + i], val,
                         __ATOMIC_RELAXED, __HIP_MEMORY_SCOPE_AGENT);
    }
  }
  __syncthreads();  // drains hdst stores (vmcnt) + LDS reusable
}

// Fused kernel (r5 structure): leaves + levels 0..7 per block (128 leaves x
// 1024 blocks); last-done block of each group of 64 runs levels 8..13; last
// group runs levels 14..17. Agent-scope (sc1) handoff as validated in r3/r5.
// Deltas vs r5: pk_add front-end (r7-validated, bit-identical), global-Wp
// projections (r7-validated), proj-l6 overlapped with h7 publish (-1 barrier).
__global__ __launch_bounds__(256, 4) void mega_kernel(
    const int* __restrict__ word_ids, const unsigned* __restrict__ embh,
    const float2* __restrict__ pw,
    const unsigned short* __restrict__ Wlf, const float* __restrict__ bl,
    const float* __restrict__ Wp, const float* __restrict__ bp,
    unsigned* __restrict__ h7g, unsigned* __restrict__ h13g,
    unsigned* __restrict__ cnts, float* __restrict__ out) {
  __shared__ _Float16 S1[64 * RS];           // dead after L1 -> aliases Eb/Ob
  __shared__ _Float16 Ea[32 * RS], Oa[32 * RS];
  __shared__ int claimS;
  _Float16* const Eb = S1;                   // 16*RS
  _Float16* const Ob = S1 + 16 * RS;         // 16*RS   (LDS total ~34.8KB)

  const int tid = threadIdx.x, lane = tid & 63;
  const int wave = __builtin_amdgcn_readfirstlane(tid >> 6);
  const int quad = lane >> 4, c16 = lane & 15;
  const int blk = blockIdx.x;

  const float bp0 = bp[0], bp1 = bp[1];

  // gather: thread = (leaf l = tid>>1, half h = tid&1); f16 row = 256B, half = 128B
  const int l = tid >> 1, hh = tid & 1;
  const long gL = (long)blk * 128 + l;
  const int wid = word_ids[gL];
  const uint4* erow = (const uint4*)(embh + (size_t)wid * 64 + hh * 32);
  uint4 w4[8];
  #pragma unroll
  for (int i = 0; i < 8; ++i) w4[i] = erow[i];

  // lvl-0 projection: precomputed exact f32 per-word values
  if (hh == 0) {
    float2 p = pw[wid];
    long pos = ((gL + 1) << 1) - 2 - __popc((unsigned)gL);
    out[2 * pos] = p.x; out[2 * pos + 1] = p.y;
  }

  {   // pair-sum with sibling leaf (thread xor 2) via packed f16 adds -> S1.
      // f16(a)+f16(b) == round_f16(f32(a)+f32(b)) (exact in f32) -> bit-identical
      // to the old upk/fadd/pk2f path (validated r7/r8). Covers all 64 dwords
      // (embh pad dwords sum to 0); dwords 64..67 of each row are never read.
    unsigned* S1d = (unsigned*)S1;
    const int m = tid >> 2;                   // S1 row (leaf pair) 0..63
    #pragma unroll
    for (int k = 0; k < 8; ++k) {
      uint4 u = w4[k], s;
      s.x = __shfl_xor(u.x, 2, 64); s.y = __shfl_xor(u.y, 2, 64);
      s.z = __shfl_xor(u.z, 2, 64); s.w = __shfl_xor(u.w, 2, 64);
      h8v hm = __builtin_bit_cast(h8v, u);
      h8v hs = __builtin_bit_cast(h8v, s);
      h8v sum = hm + hs;                      // v_pk_add_f16: correctly-rounded
      if ((tid & 2) == 0)
        *(uint4*)(S1d + (size_t)m * SD + hh * 32 + k * 4) =
            __builtin_bit_cast(uint4, sum);
    }
  }
  h8v B0[4], B1[4]; float bias0, bias1;
  load_bfrags(Wlf, bl, B0, B1, bias0, bias1, wave, quad, c16);
  __syncthreads();   // S1 ready

  // L1 (64 out)
  mfma_level(S1, nullptr, false, Ea, Oa, 64, B0, B1, bias0, bias1, lane, wave);
  __syncthreads();
  // L2 (32) + proj l1   (Eb/Ob overwrite S1 -- S1 dead after L1)
  mfma_level(Ea, Oa, true, Eb, Ob, 32, B0, B1, bias0, bias1, lane, wave);
  proj_rows(Ea, Oa, 64, Wp, bp0, bp1, 1, (long)blk * 64, out, tid);
  __syncthreads();
  // L3 (16) + proj l2
  mfma_level(Eb, Ob, true, Ea, Oa, 16, B0, B1, bias0, bias1, lane, wave);
  proj_rows(Eb, Ob, 32, Wp, bp0, bp1, 2, (long)blk * 32, out, tid);
  __syncthreads();
  // L4 (8) + proj l3
  mfma_level(Ea, Oa, true, Eb, Ob, 8, B0, B1, bias0, bias1, lane, wave);
  proj_rows(Ea, Oa, 16, Wp, bp0, bp1, 3, (long)blk * 16, out, tid);
  __syncthreads();
  // L5 (4) + proj l4
  mfma_level(Eb, Ob, true, Ea, Oa, 4, B0, B1, bias0, bias1, lane, wave);
  proj_rows(Eb, Ob, 8, Wp, bp0, bp1, 4, (long)blk * 8, out, tid);
  __syncthreads();
  // L6 (2) + proj l5
  mfma_level(Ea, Oa, true, Eb, Ob, 2, B0, B1, bias0, bias1, lane, wave);
  proj_rows(Ea, Oa, 4, Wp, bp0, bp1, 5, (long)blk * 4, out, tid);
  __syncthreads();
  // L7 (1): mfma only (proj l6 moved after the barrier)
  mfma_level(Eb, Ob, true, Ea, Oa, 1, B0, B1, bias0, bias1, lane, wave);
  __syncthreads();
  // publish h7 row (Ea row 0, agent-scope) CONCURRENT with proj l6 (Eb/Ob
  // still hold level-6 h -- untouched by L7's writes to Ea/Oa)
  if (tid < 50)
    __hip_atomic_store(&h7g[(size_t)blk * 50 + tid], ((unsigned*)Ea)[tid],
                       __ATOMIC_RELAXED, __HIP_MEMORY_SCOPE_AGENT);
  proj_rows(Eb, Ob, 2, Wp, bp0, bp1, 6, (long)blk * 2, out, tid);
  __syncthreads();   // per-wave vmcnt(0) drain: rows at coherence point

  const int g = blk >> 6;
  if (tid == 0) {
    unsigned old = __hip_atomic_fetch_add(&cnts[g], 1u, __ATOMIC_RELAXED,
                                          __HIP_MEMORY_SCOPE_AGENT);
    claimS = (old == 63u);
  }
  __syncthreads();
  if (!claimS) return;

  // ---- group claimer: levels 8..13 (+ proj 7..12), write h13 row g ----
  tree_phase(h7g + (size_t)g * 64 * 50, h13g, Ea, Oa, Eb, Ob, Wp, bp0, bp1,
             B0, B1, bias0, bias1, out, 8, 6, 64, 0, (long)g, tid, lane, wave);

  if (tid == 0) {
    unsigned old = __hip_atomic_fetch_add(&cnts[16], 1u, __ATOMIC_RELAXED,
                                          __HIP_MEMORY_SCOPE_AGENT);
    claimS = (old == 15u);
  }
  __syncthreads();
  if (!claimS) return;

  // ---- final claimer: levels 14..17 (+ proj 13..16 + final proj 17) ----
  tree_phase(h13g, nullptr, Ea, Oa, Eb, Ob, Wp, bp0, bp1,
             B0, B1, bias0, bias1, out, 14, 4, 16, 1, 0L, tid, lane, wave);
}

extern "C" void kernel_launch(void* const* d_in, const int* in_sizes, int n_in,
                              void* d_out, int out_size, void* d_ws, size_t ws_size,
                              hipStream_t stream) {
  const int*   word_ids = (const int*)  d_in[0];
  const float* emb      = (const float*)d_in[1];
  const float* Wl       = (const float*)d_in[2];
  const float* bl       = (const float*)d_in[3];
  const float* Wp       = (const float*)d_in[4];
  const float* bp       = (const float*)d_in[5];
  float* out = (float*)d_out;

  // workspace layout (~13.5 MB)
  unsigned*       embh = (unsigned*)d_ws;                            // 12,800,000 B
  float2*         pw   = (float2*)((char*)d_ws + 12800000);          //    400,000 B
  unsigned short* Wlf  = (unsigned short*)((char*)d_ws + 13200000);  //     32,768 B
  unsigned*       h7g  = (unsigned*)((char*)d_ws + 13232768);        //    204,800 B
  unsigned*       h13g = (unsigned*)((char*)d_ws + 13437568);        //      3,200 B
  unsigned*       cnts = (unsigned*)((char*)d_ws + 13440768);        //        256 B

  prep_kernel<<<1627, 256, 0, stream>>>(Wl, emb, Wp, bp, Wlf, embh, pw, cnts);
  mega_kernel<<<1024, 256, 0, stream>>>(word_ids, embh, pw, Wlf, bl, Wp, bp,
                                        h7g, h13g, cnts, out);
}

// Round 10
// 134.268 us; speedup vs baseline: 1.1316x; 1.0151x over previous
//
#include <hip/hip_runtime.h>

typedef _Float16 h8v __attribute__((ext_vector_type(8)));
typedef float f4v __attribute__((ext_vector_type(4)));

#define RS 136   // halves per LDS row (272 B, 16B-aligned, stride%32dw==4 -> 2-way max)
#define SD 68    // dwords per row

__device__ __forceinline__ unsigned pk2f(float a, float b) {
  unsigned short ha = __builtin_bit_cast(unsigned short, (_Float16)a);
  unsigned short hb = __builtin_bit_cast(unsigned short, (_Float16)b);
  return (unsigned)ha | ((unsigned)hb << 16);
}
__device__ __forceinline__ float2 upk(unsigned u) {
  _Float16 lo = __builtin_bit_cast(_Float16, (unsigned short)(u & 0xffffu));
  _Float16 hi = __builtin_bit_cast(_Float16, (unsigned short)(u >> 16));
  return make_float2((float)lo, (float)hi);
}

// prep v2 (BW-oriented): blocks [0,1563): 8 threads/word, coalesced 128B group
// loads / 64B group stores -> embh f16 rows (64 dw = 256B, dw 50..63 zero) +
// pw = exact f32 lvl-0 projection (3-step shfl_xor group reduce).
// blocks [1563,1627): Wlf f16 [128][128]; block 1563 zeroes cnts
// (re-zeroed every graph replay -> re-poison safe).
__global__ void prep_kernel(const float* __restrict__ Wl, const float* __restrict__ emb,
                            const float* __restrict__ Wp, const float* __restrict__ bp,
                            unsigned short* __restrict__ Wlf, unsigned* __restrict__ embh,
                            float2* __restrict__ pw, unsigned* __restrict__ cnts) {
  const long t = (long)blockIdx.x * 256 + threadIdx.x;
  if (t < 400000L) {              // thread = (word w, slot q in 8-lane group)
    const int w = (int)(t >> 3), q = (int)(t & 7);
    const float4* row4 = (const float4*)(emb + (size_t)w * 100);
    uint2* ed = (uint2*)(embh + (size_t)w * 64);
    float q0 = 0.f, q1 = 0.f;
    #pragma unroll
    for (int m = 0; m < 4; ++m) {
      int j = q + 8 * m;          // group covers j = 8m..8m+7 -> 128B contiguous
      if (j < 25) {
        float4 v = row4[j];
        q0 = fmaf(v.x, Wp[4*j], fmaf(v.y, Wp[4*j+1],
             fmaf(v.z, Wp[4*j+2], fmaf(v.w, Wp[4*j+3], q0))));
        q1 = fmaf(v.x, Wp[100+4*j], fmaf(v.y, Wp[100+4*j+1],
             fmaf(v.z, Wp[100+4*j+2], fmaf(v.w, Wp[100+4*j+3], q1))));
        ed[j] = make_uint2(pk2f(v.x, v.y), pk2f(v.z, v.w));
      }
    }
    if (q < 7) ed[25 + q] = make_uint2(0u, 0u);   // pad dwords 50..63
    q0 += __shfl_xor(q0, 1, 64); q0 += __shfl_xor(q0, 2, 64); q0 += __shfl_xor(q0, 4, 64);
    q1 += __shfl_xor(q1, 1, 64); q1 += __shfl_xor(q1, 2, 64); q1 += __shfl_xor(q1, 4, 64);
    if (q == 0) pw[w] = make_float2(q0 + bp[0], q1 + bp[1]);
  } else {
    long j = t - 400128L;         // Wlf region: blocks 1563..1626
    if (j >= 0 && j < 128 * 128) {
      int o = (int)(j >> 7), k = (int)(j & 127);
      _Float16 v = (_Float16)0.f;
      if (o < 100 && k < 100) v = (_Float16)Wl[o * 100 + k];
      Wlf[j] = __builtin_bit_cast(unsigned short, v);
    }
    if (blockIdx.x == 1563 && threadIdx.x >= 192 && threadIdx.x < 240)
      cnts[threadIdx.x - 192] = 0u;
  }
}

// Vectorized B-fragment load from the f16 table: 8 x 16B per thread, L1-resident.
__device__ __forceinline__ void load_bfrags(
    const unsigned short* __restrict__ Wlf, const float* __restrict__ bl,
    h8v (&B0)[4], h8v (&B1)[4], float& bias0, float& bias1,
    int wave, int quad, int c16) {
  int col0 = wave * 32 + c16;
  int col1 = col0 + 16;
  bias0 = (col0 < 100) ? 2.0f * bl[col0] : 0.f;
  bias1 = (col1 < 100) ? 2.0f * bl[col1] : 0.f;
  const _Float16* w0 = (const _Float16*)Wlf + col0 * 128 + quad * 8;
  const _Float16* w1 = (const _Float16*)Wlf + col1 * 128 + quad * 8;
  B0[0] = *(const h8v*)(w0);      B0[1] = *(const h8v*)(w0 + 32);
  B0[2] = *(const h8v*)(w0 + 64); B0[3] = *(const h8v*)(w0 + 96);
  B1[0] = *(const h8v*)(w1);      B1[1] = *(const h8v*)(w1 + 32);
  B1[2] = *(const h8v*)(w1 + 64); B1[3] = *(const h8v*)(w1 + 96);
}

// One level: nOut rows. pairMode: A = srcE[r] + srcO[r] (children 2r,2r+1);
// else A = srcE[r] (pre-summed). Output row -> (row&1 ? dstO : dstE)[row>>1].
__device__ __forceinline__ void mfma_level(
    const _Float16* srcE, const _Float16* srcO, bool pairMode,
    _Float16* dstE, _Float16* dstO, int nOut,
    const h8v (&B0)[4], const h8v (&B1)[4], float bias0, float bias1,
    int lane, int wave) {
  const int quad = lane >> 4, c16 = lane & 15;
  const int col0 = wave * 32 + c16, col1 = col0 + 16;
  const int tiles = (nOut + 15) >> 4;
  for (int rt = 0; rt < tiles; ++rt) {
    const int r = rt * 16 + c16;
    const h8v* pe = (const h8v*)(srcE + (size_t)r * RS + quad * 8);
    h8v A0, A1, A2, A3;
    if (pairMode) {
      const h8v* po = (const h8v*)(srcO + (size_t)r * RS + quad * 8);
      A0 = pe[0] + po[0];  A1 = pe[4] + po[4];
      A2 = pe[8] + po[8];  A3 = pe[12] + po[12];
    } else {
      A0 = pe[0]; A1 = pe[4]; A2 = pe[8]; A3 = pe[12];
    }
    f4v a0 = {bias0, bias0, bias0, bias0};
    f4v a1 = {bias1, bias1, bias1, bias1};
    a0 = __builtin_amdgcn_mfma_f32_16x16x32_f16(A0, B0[0], a0, 0, 0, 0);
    a0 = __builtin_amdgcn_mfma_f32_16x16x32_f16(A1, B0[1], a0, 0, 0, 0);
    a0 = __builtin_amdgcn_mfma_f32_16x16x32_f16(A2, B0[2], a0, 0, 0, 0);
    a0 = __builtin_amdgcn_mfma_f32_16x16x32_f16(A3, B0[3], a0, 0, 0, 0);
    a1 = __builtin_amdgcn_mfma_f32_16x16x32_f16(A0, B1[0], a1, 0, 0, 0);
    a1 = __builtin_amdgcn_mfma_f32_16x16x32_f16(A1, B1[1], a1, 0, 0, 0);
    a1 = __builtin_amdgcn_mfma_f32_16x16x32_f16(A2, B1[2], a1, 0, 0, 0);
    a1 = __builtin_amdgcn_mfma_f32_16x16x32_f16(A3, B1[3], a1, 0, 0, 0);
    #pragma unroll
    for (int rg = 0; rg < 4; ++rg) {
      int row = rt * 16 + quad * 4 + rg;
      _Float16* dr = ((row & 1) ? dstO : dstE) + (size_t)(row >> 1) * RS;
      dr[col0] = (_Float16)fmaxf(a0[rg], 0.f);
      dr[col1] = (_Float16)fmaxf(a1[rg], 0.f);
    }
  }
}

// Projection of ONE h-row (E/O split), compute-only (caller stores later).
// Wp from global: compile-time indices -> wave-uniform s_loads (r7-validated).
__device__ __forceinline__ float2 proj_compute(
    const _Float16* E, const _Float16* O, const float* __restrict__ Wp,
    float bp0, float bp1, int tid) {
  const unsigned* row = (const unsigned*)((tid & 1) ? O : E) + (size_t)(tid >> 1) * SD;
  float q0 = bp0, q1 = bp1;
  #pragma unroll
  for (int p = 0; p < 25; ++p) {
    uint2 u = ((const uint2*)row)[p];
    float2 a = upk(u.x), b = upk(u.y);
    q0 = fmaf(a.x, Wp[4*p], fmaf(a.y, Wp[4*p+1],
         fmaf(b.x, Wp[4*p+2], fmaf(b.y, Wp[4*p+3], q0))));
    q1 = fmaf(a.x, Wp[100+4*p], fmaf(a.y, Wp[100+4*p+1],
         fmaf(b.x, Wp[100+4*p+2], fmaf(b.y, Wp[100+4*p+3], q1))));
  }
  return make_float2(q0, q1);
}

__device__ __forceinline__ void store_out(
    float* __restrict__ out, int lvl, long gbase, int tid, float2 v) {
  long g = gbase + tid;
  long pos = ((g + 1) << (lvl + 1)) - 2 - __popc((unsigned)g);
  out[2 * pos] = v.x; out[2 * pos + 1] = v.y;
}

// Stage nIn rows (agent-scope), run NLVL levels with REGISTER-BUFFERED projs
// (tq[] static-indexed, unrolled), hdst publish + single out-store burst at the
// end -> one drain instead of NLVL+1 (removes ~NLVL barrier drains from the
// serial tail chain; only the 17 claimer blocks run this).
template <int NLVL>
__device__ void tree_phase(
    const unsigned* __restrict__ src, unsigned* __restrict__ hdst,
    _Float16* Ea, _Float16* Oa, _Float16* Eb, _Float16* Ob,
    const float* __restrict__ Wp, float bp0, float bp1,
    const h8v (&B0)[4], const h8v (&B1)[4], float bias0, float bias1,
    float* __restrict__ out, int firstLvl, int nIn, int finalProj,
    long blkg, int tid, int lane, int wave) {
  {   // stage nIn rows + zero the rest of Ea/Oa (64 virtual rows x 64 dw)
    unsigned* Ed = (unsigned*)Ea; unsigned* Od = (unsigned*)Oa;
    for (int i = tid; i < 64 * 64; i += 256) {
      int r = i >> 6, d = i & 63;
      unsigned val = (r < nIn && d < 50)
          ? __hip_atomic_load(&src[(size_t)r * 50 + d], __ATOMIC_RELAXED,
                              __HIP_MEMORY_SCOPE_AGENT)
          : 0u;
      ((r & 1) ? Od : Ed)[(r >> 1) * SD + d] = val;
    }
    unsigned* Ed2 = (unsigned*)Eb; unsigned* Od2 = (unsigned*)Ob;
    for (int i = tid; i < 32 * 64; i += 256) {
      int r = i >> 6, d = i & 63;
      ((r & 1) ? Od2 : Ed2)[(r >> 1) * SD + d] = 0u;
    }
  }
  __syncthreads();
  float2 tq[NLVL];
  _Float16 *sE = Ea, *sO = Oa, *dE = Eb, *dO = Ob;
  int n = nIn >> 1;
  #pragma unroll
  for (int p = 0; p < NLVL; ++p) {
    mfma_level(sE, sO, true, dE, dO, n, B0, B1, bias0, bias1, lane, wave);
    if (tid < 2 * n) tq[p] = proj_compute(sE, sO, Wp, bp0, bp1, tid);
    __syncthreads();
    _Float16* t;
    t = sE; sE = dE; dE = t;
    t = sO; sO = dO; dO = t;
    n >>= 1;
  }
  const int R = nIn >> NLVL;
  float2 fq;
  if (finalProj && tid < R) fq = proj_compute(sE, sO, Wp, bp0, bp1, tid);
  // hdst publish first (its latency overlaps the burst issue below)
  if (hdst) {
    for (int i = tid; i < R * 50; i += 256) {
      int r = i / 50, d = i % 50;
      unsigned val = ((const unsigned*)((r & 1) ? sO : sE))[(r >> 1) * SD + d];
      __hip_atomic_store(&hdst[(size_t)blkg * R * 50 + i], val,
                         __ATOMIC_RELAXED, __HIP_MEMORY_SCOPE_AGENT);
    }
  }
  // single out-store burst
  #pragma unroll
  for (int p = 0; p < NLVL; ++p) {
    int nR = nIn >> p;
    if (tid < nR) store_out(out, firstLvl + p - 1, blkg * nR, tid, tq[p]);
  }
  if (finalProj && tid < R)
    store_out(out, firstLvl + NLVL - 1, blkg * R, tid, fq);
  __syncthreads();  // one drain; hdst rows + out at coherence point
}

// Fused kernel (r9 structure; deltas: lag-one proj stores in the leaf ladder --
// store interval k's proj at the START of interval k+1 so the pre-barrier
// vmcnt drain finds it already retired; tree_phase register-buffered bursts).
__global__ __launch_bounds__(256, 4) void mega_kernel(
    const int* __restrict__ word_ids, const unsigned* __restrict__ embh,
    const float2* __restrict__ pw,
    const unsigned short* __restrict__ Wlf, const float* __restrict__ bl,
    const float* __restrict__ Wp, const float* __restrict__ bp,
    unsigned* __restrict__ h7g, unsigned* __restrict__ h13g,
    unsigned* __restrict__ cnts, float* __restrict__ out) {
  __shared__ _Float16 S1[64 * RS];           // dead after L1 -> aliases Eb/Ob
  __shared__ _Float16 Ea[32 * RS], Oa[32 * RS];
  __shared__ int claimS;
  _Float16* const Eb = S1;                   // 16*RS
  _Float16* const Ob = S1 + 16 * RS;         // 16*RS   (LDS total ~34.8KB)

  const int tid = threadIdx.x, lane = tid & 63;
  const int wave = __builtin_amdgcn_readfirstlane(tid >> 6);
  const int quad = lane >> 4, c16 = lane & 15;
  const int blk = blockIdx.x;

  const float bp0 = bp[0], bp1 = bp[1];

  // gather: thread = (leaf l = tid>>1, half h = tid&1); f16 row = 256B, half = 128B
  const int l = tid >> 1, hh = tid & 1;
  const long gL = (long)blk * 128 + l;
  const int wid = word_ids[gL];
  const uint4* erow = (const uint4*)(embh + (size_t)wid * 64 + hh * 32);
  uint4 w4[8];
  #pragma unroll
  for (int i = 0; i < 8; ++i) w4[i] = erow[i];

  // lvl-0 projection: precomputed exact f32 per-word values
  if (hh == 0) {
    float2 p = pw[wid];
    long pos = ((gL + 1) << 1) - 2 - __popc((unsigned)gL);
    out[2 * pos] = p.x; out[2 * pos + 1] = p.y;
  }

  {   // pair-sum with sibling leaf (thread xor 2) via packed f16 adds -> S1
      // (bit-identical to upk/fadd/pk2f: f16+f16 exact in f32; r7/r8-validated)
    unsigned* S1d = (unsigned*)S1;
    const int m = tid >> 2;                   // S1 row (leaf pair) 0..63
    #pragma unroll
    for (int k = 0; k < 8; ++k) {
      uint4 u = w4[k], s;
      s.x = __shfl_xor(u.x, 2, 64); s.y = __shfl_xor(u.y, 2, 64);
      s.z = __shfl_xor(u.z, 2, 64); s.w = __shfl_xor(u.w, 2, 64);
      h8v hm = __builtin_bit_cast(h8v, u);
      h8v hs = __builtin_bit_cast(h8v, s);
      h8v sum = hm + hs;                      // v_pk_add_f16: correctly-rounded
      if ((tid & 2) == 0)
        *(uint4*)(S1d + (size_t)m * SD + hh * 32 + k * 4) =
            __builtin_bit_cast(uint4, sum);
    }
  }
  h8v B0[4], B1[4]; float bias0, bias1;
  load_bfrags(Wlf, bl, B0, B1, bias0, bias1, wave, quad, c16);
  __syncthreads();   // S1 ready

  // ---- ladder with lag-one proj stores ----
  // L1 (64 out)
  mfma_level(S1, nullptr, false, Ea, Oa, 64, B0, B1, bias0, bias1, lane, wave);
  __syncthreads();
  // L2 (32) + compute proj l1 (Ea/Oa)
  mfma_level(Ea, Oa, true, Eb, Ob, 32, B0, B1, bias0, bias1, lane, wave);
  float2 c1; if (tid < 64) c1 = proj_compute(Ea, Oa, Wp, bp0, bp1, tid);
  __syncthreads();
  // st l1 | L3 (16) + compute proj l2 (Eb/Ob)
  if (tid < 64) store_out(out, 1, (long)blk * 64, tid, c1);
  mfma_level(Eb, Ob, true, Ea, Oa, 16, B0, B1, bias0, bias1, lane, wave);
  float2 c2; if (tid < 32) c2 = proj_compute(Eb, Ob, Wp, bp0, bp1, tid);
  __syncthreads();
  // st l2 | L4 (8) + compute proj l3 (Ea/Oa)
  if (tid < 32) store_out(out, 2, (long)blk * 32, tid, c2);
  mfma_level(Ea, Oa, true, Eb, Ob, 8, B0, B1, bias0, bias1, lane, wave);
  float2 c3; if (tid < 16) c3 = proj_compute(Ea, Oa, Wp, bp0, bp1, tid);
  __syncthreads();
  // st l3 | L5 (4) + compute proj l4 (Eb/Ob)
  if (tid < 16) store_out(out, 3, (long)blk * 16, tid, c3);
  mfma_level(Eb, Ob, true, Ea, Oa, 4, B0, B1, bias0, bias1, lane, wave);
  float2 c4; if (tid < 8) c4 = proj_compute(Eb, Ob, Wp, bp0, bp1, tid);
  __syncthreads();
  // st l4 | L6 (2) + compute proj l5 (Ea/Oa)
  if (tid < 8) store_out(out, 4, (long)blk * 8, tid, c4);
  mfma_level(Ea, Oa, true, Eb, Ob, 2, B0, B1, bias0, bias1, lane, wave);
  float2 c5; if (tid < 4) c5 = proj_compute(Ea, Oa, Wp, bp0, bp1, tid);
  __syncthreads();
  // st l5 | L7 (1): mfma only
  if (tid < 4) store_out(out, 5, (long)blk * 4, tid, c5);
  mfma_level(Eb, Ob, true, Ea, Oa, 1, B0, B1, bias0, bias1, lane, wave);
  __syncthreads();
  // publish h7 (Ea row 0, agent-scope) | proj l6 from Eb/Ob (level-6 h intact)
  if (tid < 50)
    __hip_atomic_store(&h7g[(size_t)blk * 50 + tid], ((unsigned*)Ea)[tid],
                       __ATOMIC_RELAXED, __HIP_MEMORY_SCOPE_AGENT);
  if (tid < 2) {
    float2 c6 = proj_compute(Eb, Ob, Wp, bp0, bp1, tid);
    store_out(out, 6, (long)blk * 2, tid, c6);
  }
  __syncthreads();   // drains h7g + c6: rows at coherence point

  const int g = blk >> 6;
  if (tid == 0) {
    unsigned old = __hip_atomic_fetch_add(&cnts[g], 1u, __ATOMIC_RELAXED,
                                          __HIP_MEMORY_SCOPE_AGENT);
    claimS = (old == 63u);
  }
  __syncthreads();
  if (!claimS) return;

  // ---- group claimer: levels 8..13 (+ proj 7..12), write h13 row g ----
  tree_phase<6>(h7g + (size_t)g * 64 * 50, h13g, Ea, Oa, Eb, Ob, Wp, bp0, bp1,
                B0, B1, bias0, bias1, out, 8, 64, 0, (long)g, tid, lane, wave);

  if (tid == 0) {
    unsigned old = __hip_atomic_fetch_add(&cnts[16], 1u, __ATOMIC_RELAXED,
                                          __HIP_MEMORY_SCOPE_AGENT);
    claimS = (old == 15u);
  }
  __syncthreads();
  if (!claimS) return;

  // ---- final claimer: levels 14..17 (+ proj 13..16 + final proj 17) ----
  tree_phase<4>(h13g, nullptr, Ea, Oa, Eb, Ob, Wp, bp0, bp1,
                B0, B1, bias0, bias1, out, 14, 16, 1, 0L, tid, lane, wave);
}

extern "C" void kernel_launch(void* const* d_in, const int* in_sizes, int n_in,
                              void* d_out, int out_size, void* d_ws, size_t ws_size,
                              hipStream_t stream) {
  const int*   word_ids = (const int*)  d_in[0];
  const float* emb      = (const float*)d_in[1];
  const float* Wl       = (const float*)d_in[2];
  const float* bl       = (const float*)d_in[3];
  const float* Wp       = (const float*)d_in[4];
  const float* bp       = (const float*)d_in[5];
  float* out = (float*)d_out;

  // workspace layout (~13.5 MB)
  unsigned*       embh = (unsigned*)d_ws;                            // 12,800,000 B
  float2*         pw   = (float2*)((char*)d_ws + 12800000);          //    400,000 B
  unsigned short* Wlf  = (unsigned short*)((char*)d_ws + 13200000);  //     32,768 B
  unsigned*       h7g  = (unsigned*)((char*)d_ws + 13232768);        //    204,800 B
  unsigned*       h13g = (unsigned*)((char*)d_ws + 13437568);        //      3,200 B
  unsigned*       cnts = (unsigned*)((char*)d_ws + 13440768);        //        256 B

  prep_kernel<<<1627, 256, 0, stream>>>(Wl, emb, Wp, bp, Wlf, embh, pw, cnts);
  mega_kernel<<<1024, 256, 0, stream>>>(word_ids, embh, pw, Wlf, bl, Wp, bp,
                                        h7g, h13g, cnts, out);
}